// Round 4
// baseline (240.157 us; speedup 1.0000x reference)
//
#include <hip/hip_runtime.h>

typedef _Float16 half8  __attribute__((ext_vector_type(8)));
typedef _Float16 half4  __attribute__((ext_vector_type(4)));
typedef float    float4v __attribute__((ext_vector_type(4)));
typedef float    float8v __attribute__((ext_vector_type(8)));
typedef float    float16v __attribute__((ext_vector_type(16)));

#define N_ROWS  65536   // 64*32*32
#define N_CODES 1024
#define DIM     256
#define BM      64      // rows per block
#define NBLKS   (N_ROWS / BM)   // 1024

// ---- prep: one wave per code. ||e||^2 and hi/lo f16 split written in MFMA
// B-fragment order for 32x32x16: frag block b = nt*16 + kstep holds 1024
// halves [hi 512 | lo 512]; within: lane' = (code&31) + 32*((k>>3)&1),
// elem j = k&7.  (nt = code>>5, kstep = k>>4)
__global__ __launch_bounds__(64)
void vq_prep(const float* __restrict__ emb, float* __restrict__ e_norm,
             _Float16* __restrict__ e_frag) {
    const int c = blockIdx.x, lane = threadIdx.x;
    float4v v = ((const float4v*)(emb + (size_t)c * DIM))[lane];
    half4 h, l;
    float ss = 0.f;
    #pragma unroll
    for (int j = 0; j < 4; ++j) {
        float x = v[j];
        ss += x * x;
        _Float16 hh = (_Float16)x;
        h[j] = hh;
        l[j] = (_Float16)(x - (float)hh);
    }
    // this lane's 4 elements: k = lane*4 .. +3  -> kstep=lane>>2,
    // khalf=(lane>>1)&1, j-base=(lane&1)*4
    const int kstep = lane >> 2;
    const int khalf = (lane >> 1) & 1;
    const int jb    = (lane & 1) * 4;
    _Float16* p = e_frag + ((size_t)((c >> 5) * 16 + kstep)) * 1024
                + ((c & 31) + 32 * khalf) * 8 + jb;
    *(half4*)p = h;
    *(half4*)(p + 512) = l;
    #pragma unroll
    for (int m = 32; m >= 1; m >>= 1) ss += __shfl_xor(ss, m, 64);
    if (lane == 0) e_norm[c] = ss;
}

// ---- main: 256 threads (4 waves), BM=64 rows, full K in LDS (~72.5 KB ->
// 2 blocks/CU). 32x32x16 MFMA: higher FLOP/cyc ceiling, half the instr
// count, and B-frags per kstep = 32 VGPR so an explicit B double-buffer
// fits (acc[2][4] = 128 AGPR + 64 VGPR B + 16 A). Each wave: all 64 rows
// x 256 codes in 2 passes of 128 codes (4 nt-tiles of 32).
__global__ __launch_bounds__(256, 2)
void vq_main(const float* __restrict__ z,
             const _Float16* __restrict__ e_frag,
             const float* __restrict__ e_norm,
             const float* __restrict__ emb,
             float* __restrict__ zq,
             float* __restrict__ idxf,
             int fused_gather) {
    __shared__ _Float16 sA[32 * 2 * 512];     // [mt*16+kstep][hi|lo][512] = 64 KB
    __shared__ float    s_nrm[N_CODES];       // 4 KB
    __shared__ float2   s_best[BM][5];        // 4 wave slots + pad: 2.5 KB
    __shared__ int      s_idx[BM];

    const int t = threadIdx.x;
    const int w = t >> 6, lane = t & 63, quad = lane >> 4, l15 = lane & 15;
    const int l31 = lane & 31, half = lane >> 5;
    const int rowblk = blockIdx.x * BM;

    s_nrm[t]       = e_norm[t];
    s_nrm[t + 256] = e_norm[t + 256];
    s_nrm[t + 512] = e_norm[t + 512];
    s_nrm[t + 768] = e_norm[t + 768];

    // ---- B preload for pass 0 / kstep 0 (global, no LDS dep: issue before
    // staging so L2 latency hides under the z loads + convert).
    half8 bh[2][4], bl[2][4];
    {
        const int ntbase0 = w * 8;
        #pragma unroll
        for (int nt = 0; nt < 4; ++nt) {
            const _Float16* bp = e_frag + ((size_t)((ntbase0 + nt) * 16 + 0)) * 1024 + lane * 8;
            bh[0][nt] = *(const half8*)bp;
            bl[0][nt] = *(const half8*)(bp + 512);
        }
    }

    // ---- stage A: wave w loads rows w*16..w*16+15, converts to hi/lo f16,
    // writes 32x32x16 A-frag order: block (mt=row>>5, kstep=k>>4),
    // lane' = (row&31) + 32*((k>>3)&1), elem j = k&7.
    #pragma unroll
    for (int i = 0; i < 8; ++i) {
        const int row = w * 16 + l15;
        const int col = i * 32 + quad * 8;            // 8 consecutive k
        float8v v = *(const float8v*)(z + (size_t)(rowblk + row) * DIM + col);
        half8 h, lo;
        #pragma unroll
        for (int j = 0; j < 8; ++j) {
            float x = v[j];
            _Float16 hh = (_Float16)x;
            h[j] = hh;
            lo[j] = (_Float16)(x - (float)hh);
        }
        const int mt    = w >> 1;
        const int rloc  = (w & 1) * 16 + l15;         // row & 31
        const int kstep = i * 2 + (quad >> 1);
        const int khalf = quad & 1;
        _Float16* p = sA + (size_t)((mt * 16 + kstep) * 2) * 512
                    + (rloc + 32 * khalf) * 8;
        *(half8*)p = h;
        *(half8*)(p + 512) = lo;
    }
    __syncthreads();   // the only compute barrier

    for (int pass = 0; pass < 2; ++pass) {
        const int ntbase = w * 8 + pass * 4;

        // refill buf0 with this pass's kstep=0 frags (pass 0 preloaded)
        if (pass) {
            #pragma unroll
            for (int nt = 0; nt < 4; ++nt) {
                const _Float16* bp = e_frag + ((size_t)((ntbase + nt) * 16 + 0)) * 1024 + lane * 8;
                bh[0][nt] = *(const half8*)bp;
                bl[0][nt] = *(const half8*)(bp + 512);
            }
        }

        float16v acc[2][4] = {};

        #pragma unroll
        for (int ksp = 0; ksp < 16; ++ksp) {
            const int cur = ksp & 1, nxt = cur ^ 1;
            // prefetch next kstep's B (L2) under this kstep's MFMAs
            if (ksp < 15) {
                #pragma unroll
                for (int nt = 0; nt < 4; ++nt) {
                    const _Float16* bp = e_frag + ((size_t)((ntbase + nt) * 16 + (ksp + 1))) * 1024 + lane * 8;
                    bh[nxt][nt] = *(const half8*)bp;
                    bl[nxt][nt] = *(const half8*)(bp + 512);
                }
            }
            // A frags from LDS (lane-linear, conflict-free)
            half8 ah[2], al[2];
            #pragma unroll
            for (int mt = 0; mt < 2; ++mt) {
                const _Float16* ap = sA + (size_t)((mt * 16 + ksp) * 2) * 512 + lane * 8;
                ah[mt] = *(const half8*)ap;
                al[mt] = *(const half8*)(ap + 512);
            }
            __builtin_amdgcn_s_setprio(1);
            // three sweeps of 8 independent tiles: dep chains 3-deep,
            // distance 8 -> MFMA pipe stays fed
            #pragma unroll
            for (int mt = 0; mt < 2; ++mt)
                #pragma unroll
                for (int nt = 0; nt < 4; ++nt)
                    acc[mt][nt] = __builtin_amdgcn_mfma_f32_32x32x16_f16(ah[mt], bh[cur][nt], acc[mt][nt], 0, 0, 0);
            #pragma unroll
            for (int mt = 0; mt < 2; ++mt)
                #pragma unroll
                for (int nt = 0; nt < 4; ++nt)
                    acc[mt][nt] = __builtin_amdgcn_mfma_f32_32x32x16_f16(ah[mt], bl[cur][nt], acc[mt][nt], 0, 0, 0);
            #pragma unroll
            for (int mt = 0; mt < 2; ++mt)
                #pragma unroll
                for (int nt = 0; nt < 4; ++nt)
                    acc[mt][nt] = __builtin_amdgcn_mfma_f32_32x32x16_f16(al[mt], bh[cur][nt], acc[mt][nt], 0, 0, 0);
            __builtin_amdgcn_s_setprio(0);
        }

        // ---- pass epilogue: score = ||e||^2 - 2*dot; per-row argmin.
        // C/D layout (32x32, verified): col = lane&31,
        // row = (reg&3) + 8*(reg>>2) + 4*(lane>>5).
        float nrm[4]; int cg[4];
        #pragma unroll
        for (int nt = 0; nt < 4; ++nt) {
            cg[nt]  = (ntbase + nt) * 32 + l31;
            nrm[nt] = s_nrm[cg[nt]];
        }
        #pragma unroll
        for (int mt = 0; mt < 2; ++mt) {
            #pragma unroll
            for (int r = 0; r < 16; ++r) {
                float bs = nrm[0] - 2.0f * acc[mt][0][r]; int bi = cg[0];
                #pragma unroll
                for (int nt = 1; nt < 4; ++nt) {
                    float s = nrm[nt] - 2.0f * acc[mt][nt][r];
                    if (s < bs) { bs = s; bi = cg[nt]; }   // ascending codes: strict <
                }
                #pragma unroll
                for (int m = 1; m < 32; m <<= 1) {   // reduce the 32 cols (same row)
                    float s2 = __shfl_xor(bs, m, 64);
                    int   i2 = __shfl_xor(bi, m, 64);
                    if (s2 < bs || (s2 == bs && i2 < bi)) { bs = s2; bi = i2; }
                }
                if (l31 == 0) {   // lanes 0 and 32: rows for half=0/1
                    const int row = mt * 32 + (r & 3) + 8 * (r >> 2) + 4 * half;
                    if (pass == 0) {
                        float2 pr; pr.x = bs; pr.y = (float)bi;
                        s_best[row][w] = pr;
                    } else {
                        // later pass has strictly higher codes: strict <
                        float2 pv = s_best[row][w];
                        if (bs < pv.x) {
                            float2 pr; pr.x = bs; pr.y = (float)bi;
                            s_best[row][w] = pr;
                        }
                    }
                }
            }
        }
    }
    __syncthreads();

    // ---- block reduce over 4 wave slots/row; write indices
    if (t < BM) {
        float2 p0 = s_best[t][0];
        float bs = p0.x, bi = p0.y;
        #pragma unroll
        for (int s = 1; s < 4; ++s) {
            float2 pv = s_best[t][s];
            if (pv.x < bs || (pv.x == bs && pv.y < bi)) { bs = pv.x; bi = pv.y; }
        }
        s_idx[t] = (int)bi;
        idxf[rowblk + t] = bi;
    }

    if (!fused_gather) return;
    __syncthreads();

    // ---- fused gather: 4 threads/row, 16 float4 each (64 rows, 256 threads)
    const float4v* emb4 = (const float4v*)emb;
    float4v* zq4 = (float4v*)zq;
    const int rr = t >> 2, cb = t & 3;
    const int code = s_idx[rr];
    #pragma unroll
    for (int i = 0; i < 16; ++i) {
        const int chunk = cb + i * 4;
        zq4[(size_t)(rowblk + rr) * 64 + chunk] = emb4[(size_t)code * 64 + chunk];
    }
}

// ---- fallback gather (only when e_frag had to live in d_out): wave per row
__global__ __launch_bounds__(256)
void vq_gather(const float* __restrict__ emb,
               const float* __restrict__ idxf,
               float* __restrict__ zq) {
    const int tid  = blockIdx.x * 256 + threadIdx.x;
    const int r    = tid >> 6;
    const int lane = tid & 63;
    const int idx  = (int)idxf[r];
    const float4* ep = (const float4*)(emb + (size_t)idx * DIM);
    ((float4*)(zq + (size_t)r * DIM))[lane] = ep[lane];
}

extern "C" void kernel_launch(void* const* d_in, const int* in_sizes, int n_in,
                              void* d_out, int out_size, void* d_ws, size_t ws_size,
                              hipStream_t stream) {
    const float* z   = (const float*)d_in[0];   // (64,32,32,256) fp32
    const float* emb = (const float*)d_in[1];   // (1024,256) fp32

    float* zq   = (float*)d_out;                        // output 0: 16,777,216 f
    float* idxf = zq + (size_t)N_ROWS * DIM;            // output 1: 65,536 f

    // scratch: e_norm (4 KB pad) + e_frag (1 MB)
    const size_t need = 4096 + (size_t)N_CODES * DIM * 2 * sizeof(_Float16);
    const int in_ws = (ws_size >= need);
    char* base = in_ws ? (char*)d_ws : (char*)d_out;    // fallback: zq area; then
                                                        // gather must be a later kernel
    float*    e_norm = (float*)base;
    _Float16* e_frag = (_Float16*)(base + 4096);

    vq_prep<<<N_CODES, 64, 0, stream>>>(emb, e_norm, e_frag);
    vq_main<<<NBLKS, 256, 0, stream>>>(z, e_frag, e_norm, emb, zq, idxf, in_ws);
    if (!in_ws)
        vq_gather<<<(N_ROWS * 64) / 256, 256, 0, stream>>>(emb, idxf, zq);
}